// Round 9
// baseline (39.402 us; speedup 1.0000x reference)
//
#include <hip/hip_runtime.h>
#include <hip/hip_bf16.h>

typedef __attribute__((ext_vector_type(8))) short bf16x8;   // 8 bf16 (4 VGPRs)
typedef __attribute__((ext_vector_type(4))) float f32x4;    // MFMA accumulator

#define CA_EPS 1e-6f

__device__ __forceinline__ unsigned short f2bf(float f) {
  // round-to-nearest-even bf16
  unsigned u = __float_as_uint(f);
  u += 0x7fffu + ((u >> 16) & 1u);
  return (unsigned short)(u >> 16);
}

// ONE fused kernel: C[b][n][m] = cos(A1*X, A2*Y) pairwise.
// Each block owns a 256x256 output region of batch b (grid 8x8x8 = 512
// blocks, 1D, b = id&7 so batch == XCD: all f32 input re-reads are local
// L2 hits -- per-XCD working set 4.2 MB < 4 MB... ~fits; first touch HBM).
//
// Per block:
//  - gate+L2-normalize its 256-row Y-slab (f32 from L2) -> bf16 -> ldsB
//    (XOR-swizzled rows, rule #21-consistent with fragment reads)
//  - hoist B fragments to registers (wave's 32 cols, all K) -- ds_read
//  - 4 tiles of 64x256: gate+normalize the 64-row X-tile -> ldsA, barrier,
//    16 ds_read_b128 + 32 MFMA per wave, store, barrier.
// Normalization is recomputed per block (8x for X rows, 32x for Y rows) --
// redundant VALU+L2 reads are cheaper than a separate kernel's 42 MB HBM
// pass + launch gap + ws round-trip.
// LDS = 64 KB (B) + 16 KB (A) = 80 KB -> 2 blocks/CU.
__global__ void __launch_bounds__(512, 4) cosine_fused_kernel(
    const float* __restrict__ X, const float* __restrict__ Y,
    const float* __restrict__ A1, const float* __restrict__ A2,
    float* __restrict__ C) {
  __shared__ unsigned short ldsB[256 * 128];  // 64 KB normalized Y-slab
  __shared__ unsigned short ldsA[64 * 128];   // 16 KB normalized X-tile

  const int tid = threadIdx.x;
  const int id = blockIdx.x;
  const int b = id & 7;    // batch == XCD (round-robin dispatch)
  const int u = id >> 3;   // 0..63 within batch
  const int tg = u >> 3;   // 256-row group (8)
  const int tm = u & 7;    // 256-col group (8)

  const int l = tid & 31;       // lane-in-row for norm phases (float4/lane)
  const int nr = tid >> 5;      // row-in-pass (16 rows per pass)

  // ---- Normalize one row: read gated f32, reduce, write bf16 to LDS ----
  auto norm_row = [&](const float* src, const float* gate, size_t grow,
                      unsigned short* lds, int lrow) {
    const size_t off = grow * 128 + l * 4;
    const float4 x = *(const float4*)(src + off);
    const float4 a = *(const float4*)(gate + off);
    float g0 = x.x * a.x, g1 = x.y * a.y, g2 = x.z * a.z, g3 = x.w * a.w;
    float ss = g0 * g0 + g1 * g1 + g2 * g2 + g3 * g3;
#pragma unroll
    for (int o = 16; o; o >>= 1) ss += __shfl_xor(ss, o);
    float inv = 1.0f / sqrtf(fmaxf(ss, CA_EPS));
    ushort4 ov;
    ov.x = f2bf(g0 * inv);
    ov.y = f2bf(g1 * inv);
    ov.z = f2bf(g2 * inv);
    ov.w = f2bf(g3 * inv);
    // Swizzled LDS write: 16B chunk c = l>>1 within the row, chunk ^= row&7
    // (same involution the fragment reads apply).
    int c = l >> 1;
    *(ushort4*)(&lds[lrow * 128 + ((c ^ (lrow & 7)) << 3) + (l & 1) * 4]) = ov;
  };

  // ---- Phase 0: normalize B-slab (256 rows) and A-tile 0 (64 rows) ----
#pragma unroll
  for (int p = 0; p < 16; ++p) {
    int row = p * 16 + nr;  // 0..255
    norm_row(Y, A2, (size_t)b * 2048 + (size_t)tm * 256 + row, ldsB, row);
  }
#pragma unroll
  for (int p = 0; p < 4; ++p) {
    int row = p * 16 + nr;  // 0..63
    norm_row(X, A1, (size_t)b * 2048 + (size_t)tg * 256 + row, ldsA, row);
  }
  __syncthreads();

  // ---- Hoist B fragments (iteration-invariant, 8 ds_read_b128) ----
  const int lane = tid & 63;
  const int w = tid >> 6;     // wave 0..7 = 32-col slab
  const int r16 = lane & 15;  // frag row (A) / frag col (B,C)
  const int kq = lane >> 4;   // k-quarter 0..3

  bf16x8 bfr[4][2];
#pragma unroll
  for (int kk = 0; kk < 4; ++kk) {
    int kc = kk * 4 + kq;
#pragma unroll
    for (int ni = 0; ni < 2; ++ni) {
      int r = w * 32 + ni * 16 + r16;
      bfr[kk][ni] = *(const bf16x8*)(&ldsB[r * 128 + ((kc ^ (r & 7)) * 8)]);
    }
  }

  // ---- 4 tiles of 64x256 ----
#pragma unroll
  for (int t = 0; t < 4; ++t) {
    f32x4 acc[4][2] = {};
#pragma unroll
    for (int kk = 0; kk < 4; ++kk) {
      int kc = kk * 4 + kq;
      bf16x8 af[4];
#pragma unroll
      for (int mi = 0; mi < 4; ++mi) {
        int r = mi * 16 + r16;
        af[mi] = *(const bf16x8*)(&ldsA[r * 128 + ((kc ^ (r & 7)) * 8)]);
      }
#pragma unroll
      for (int mi = 0; mi < 4; ++mi)
#pragma unroll
        for (int ni = 0; ni < 2; ++ni)
          acc[mi][ni] = __builtin_amdgcn_mfma_f32_16x16x32_bf16(
              af[mi], bfr[kk][ni], acc[mi][ni], 0, 0, 0);
    }

    // Store tile t (R4-proven epilogue). C/D layout (m89-verified):
    // col = lane&15, row = (lane>>4)*4 + reg.
    float* Cb = C + ((size_t)b * 2048 + (size_t)tg * 256 + t * 64) * 2048 +
                (size_t)tm * 256 + w * 32;
#pragma unroll
    for (int mi = 0; mi < 4; ++mi)
#pragma unroll
      for (int j = 0; j < 4; ++j) {
        float* crow = Cb + (size_t)(mi * 16 + kq * 4 + j) * 2048 + r16;
#pragma unroll
        for (int ni = 0; ni < 2; ++ni) crow[ni * 16] = acc[mi][ni][j];
      }

    // Normalize next A-tile into ldsA (after all waves finished reading it).
    if (t < 3) {
      __syncthreads();
#pragma unroll
      for (int p = 0; p < 4; ++p) {
        int row = p * 16 + nr;
        norm_row(X, A1,
                 (size_t)b * 2048 + (size_t)tg * 256 + (t + 1) * 64 + row,
                 ldsA, row);
      }
      __syncthreads();
    }
  }
}

extern "C" void kernel_launch(void* const* d_in, const int* in_sizes, int n_in,
                              void* d_out, int out_size, void* d_ws, size_t ws_size,
                              hipStream_t stream) {
  const float* X  = (const float*)d_in[0];
  const float* Y  = (const float*)d_in[1];
  const float* A1 = (const float*)d_in[2];
  const float* A2 = (const float*)d_in[3];
  float* C = (float*)d_out;

  // 512 blocks: b = id&7 (XCD-local batch), 8x8 panel groups per batch.
  cosine_fused_kernel<<<dim3(512), dim3(512), 0, stream>>>(X, Y, A1, A2, C);
}